// Round 12
// baseline (143.603 us; speedup 1.0000x reference)
//
#include <hip/hip_runtime.h>

// TotalVariationLoss: mean of the 8 smallest non-self squared distances per
// point (B=4, N=8192, 3D), averaged. Round 12: QL=2 queries/lane amortizes
// each LDS-broadcast candidate over 2 queries (delivery-pipe relief), and a
// 9-slot list absorbs the self-distance (0) so the scan needs NO exclusion
// logic; the self-zero is dropped post-scan by the unique owning wave.

constexpr int B_     = 4;
constexpr int N_     = 8192;
constexpr int KNN    = 8;
constexpr int NS     = KNN + 1;        // 9 slots (self-zero absorbed)
constexpr int WAVES  = 16;
constexpr int BLOCK  = WAVES * 64;     // 1024 threads
constexpr int TILE   = 1024;           // candidates staged per tile
constexpr int NTILES = N_ / TILE;      // 8
constexpr int QL     = 2;              // queries per lane
constexpr int QG     = 64 * QL;        // 128 queries per block

#define CE(a, b) { const float _lo = fminf(a, b); b = fmaxf(a, b); a = _lo; }
#define MED3 __builtin_amdgcn_fmed3f

// insert dd into sorted src[0..8] -> dst[0..8] (9 independent ops)
#define INS9(dst, src, dd)                        \
    dst[0] = fminf(src[0], dd);                   \
    dst[1] = MED3(src[0], src[1], dd);            \
    dst[2] = MED3(src[1], src[2], dd);            \
    dst[3] = MED3(src[2], src[3], dd);            \
    dst[4] = MED3(src[3], src[4], dd);            \
    dst[5] = MED3(src[4], src[5], dd);            \
    dst[6] = MED3(src[5], src[6], dd);            \
    dst[7] = MED3(src[6], src[7], dd);            \
    dst[8] = MED3(src[7], src[8], dd);

__global__ __launch_bounds__(256)
void prepack_kernel(const float* __restrict__ pts, float4* __restrict__ p4) {
    const int i = blockIdx.x * 256 + threadIdx.x;
    if (i < B_ * N_) {
        const float x = pts[i * 3 + 0], y = pts[i * 3 + 1], z = pts[i * 3 + 2];
        p4[i] = make_float4(x, y, z, fmaf(x, x, fmaf(y, y, z * z)));
    }
}

__global__ __launch_bounds__(BLOCK, 2)
void knn_tv_kernel(const float4* __restrict__ p4, float* __restrict__ out) {
    __shared__ float4 tile[TILE];                          // 16 KiB
    __shared__ float  lists[(WAVES - 1) * 64][QL][KNN + 1];// 69.1 KiB

    const int tid   = threadIdx.x;
    const int lane  = tid & 63;
    const int w     = tid >> 6;               // wave id == tile-slice id
    const int g     = blockIdx.x;
    const int b     = g >> 6;                 // 64 query-groups per batch
    const int qbase = (g & 63) * QG;          // 128-aligned

    const float4* __restrict__ base = p4 + b * N_;
    const float4 q0 = base[qbase + lane];             // coalesced
    const float4 q1 = base[qbase + 64 + lane];
    const float a0x = -2.0f * q0.x, a0y = -2.0f * q0.y, a0z = -2.0f * q0.z;
    const float a1x = -2.0f * q1.x, a1y = -2.0f * q1.y, a1z = -2.0f * q1.z;

    // self positions: q0 -> (tile ts, wave ws0, j=lane); q1 -> (ts, ws0+1, j=lane)
    const int ts  = qbase >> 10;
    const int ws0 = (qbase & (TILE - 1)) >> 6;

    float h0[NS], g0[NS], h1[NS], g1[NS];
#pragma unroll
    for (int k = 0; k < NS; ++k) { h0[k] = 1e30f; h1[k] = 1e30f; g0[k] = 1e30f; g1[k] = 1e30f; }

    for (int t = 0; t < NTILES; ++t) {
        __syncthreads();                       // previous tile fully consumed
        tile[tid] = base[t * TILE + tid];      // 1 float4/thread, coalesced
        __syncthreads();
        const float4* __restrict__ slice = &tile[w * 64];

#pragma unroll 4
        for (int j = 0; j < 64; j += 2) {      // pair of candidates: h->g->h
            const float4 sa = slice[j];        // uniform addr -> LDS broadcast
            const float4 sb = slice[j + 1];
            const float da0 = fmaf(a0x, sa.x, fmaf(a0y, sa.y, fmaf(a0z, sa.z, q0.w + sa.w)));
            const float da1 = fmaf(a1x, sa.x, fmaf(a1y, sa.y, fmaf(a1z, sa.z, q1.w + sa.w)));
            const float db0 = fmaf(a0x, sb.x, fmaf(a0y, sb.y, fmaf(a0z, sb.z, q0.w + sb.w)));
            const float db1 = fmaf(a1x, sb.x, fmaf(a1y, sb.y, fmaf(a1z, sb.z, q1.w + sb.w)));
            INS9(g0, h0, da0)  INS9(h0, g0, db0)
            INS9(g1, h1, da1)  INS9(h1, g1, db1)
        }
    }

    // Drop the self-zero: the wave that scanned the query's own 64-slice has
    // d2(self)=0 guaranteed at h[0]; it keeps h[1..8], others keep h[0..7].
    float f0[KNN], f1[KNN];
#pragma unroll
    for (int k = 0; k < KNN; ++k) f0[k] = h0[k];
#pragma unroll
    for (int k = 0; k < KNN; ++k) f1[k] = h1[k];
    if (w == ws0) {
#pragma unroll
        for (int k = 0; k < KNN; ++k) f0[k] = h0[k + 1];
    }
    if (w == ws0 + 1) {
#pragma unroll
        for (int k = 0; k < KNN; ++k) f1[k] = h1[k + 1];
    }

    // merge the 16 per-wave sorted 8-lists (per query)
    if (w > 0) {
#pragma unroll
        for (int k = 0; k < KNN; ++k) {
            lists[(w - 1) * 64 + lane][0][k] = f0[k];
            lists[(w - 1) * 64 + lane][1][k] = f1[k];
        }
    }
    __syncthreads();
    if (w == 0) {
        for (int ww = 0; ww < WAVES - 1; ++ww) {
#pragma unroll
            for (int qi = 0; qi < QL; ++qi) {
                float e[KNN];
                float* h = qi ? f1 : f0;
#pragma unroll
                for (int k = 0; k < KNN; ++k) e[k] = lists[ww * 64 + lane][qi][k];
                // top-8 of two sorted lists: min vs reversed -> bitonic cleanup
                float m0 = fminf(h[0], e[7]), m1 = fminf(h[1], e[6]);
                float m2 = fminf(h[2], e[5]), m3 = fminf(h[3], e[4]);
                float m4 = fminf(h[4], e[3]), m5 = fminf(h[5], e[2]);
                float m6 = fminf(h[6], e[1]), m7 = fminf(h[7], e[0]);
                CE(m0, m4) CE(m1, m5) CE(m2, m6) CE(m3, m7)
                CE(m0, m2) CE(m1, m3) CE(m4, m6) CE(m5, m7)
                CE(m0, m1) CE(m2, m3) CE(m4, m5) CE(m6, m7)
                h[0] = m0; h[1] = m1; h[2] = m2; h[3] = m3;
                h[4] = m4; h[5] = m5; h[6] = m6; h[7] = m7;
            }
        }
        float qsum = 0.0f;
#pragma unroll
        for (int k = 0; k < KNN; ++k) qsum += f0[k] + f1[k];
#pragma unroll
        for (int off = 32; off >= 1; off >>= 1) qsum += __shfl_xor(qsum, off, 64);
        if (lane == 0)
            atomicAdd(out, qsum * (1.0f / ((float)B_ * N_ * KNN)));
    }
}

extern "C" void kernel_launch(void* const* d_in, const int* in_sizes, int n_in,
                              void* d_out, int out_size, void* d_ws, size_t ws_size,
                              hipStream_t stream) {
    const float* pts = (const float*)d_in[0];
    float* out = (float*)d_out;
    float4* p4 = (float4*)d_ws;               // 4*8192*16 = 512 KiB scratch

    hipMemsetAsync(out, 0, (size_t)out_size * sizeof(float), stream);
    prepack_kernel<<<(B_ * N_ + 255) / 256, 256, 0, stream>>>(pts, p4);
    knn_tv_kernel<<<B_ * (N_ / QG), BLOCK, 0, stream>>>(p4, out);  // 256 blocks
}